// Round 2
// baseline (803.361 us; speedup 1.0000x reference)
//
#include <hip/hip_runtime.h>
#include <cstddef>

// Problem constants: N=64 state dim, L=16384 seq, BATCH=512, chunk m=128.
static constexpr int RCN = 512 * 128;   // 65536 (row, chunk) pairs

// ws layout (float offsets)
static constexpr size_t WS_W  = 0;       // W[r][i] = (Ab^r Bb)_i, 128x64 fp32
static constexpr size_t WS_G  = 8192;    // fused weights G, 192x128 fp32
static constexpr size_t WS_MD = 32768;   // M = Ab^128, 64x64 DOUBLE (8192 floats)
static constexpr size_t WS_BV = 40960;   // chunk vectors b, RCN x 64 fp32
static constexpr size_t WS_X  = WS_BV + (size_t)RCN * 64;  // chunk states X, RCN x 64 fp32

// ---------------------------------------------------------------------------
// Kernel A: discretize + build all weights, entirely in fp64 and LDS.
//   N1 = sum_{k=0}^{13} (hA)^k  (Neumann/Horner; ||hA|| <= ~0.115 -> err ~1e-13)
//   Ab = 2*N1 - I ; Bb = step*N1*B
//   Sequential recurrences: w_r = Ab w_{r-1} (W), h_r = h_{r-1} Ab (H rows of G),
//   K[r] = C . w_r ; M = Ab^128 by 7 in-place squarings.
// No global read-back inside the kernel; everything flows through LDS.
// ---------------------------------------------------------------------------
__global__ __launch_bounds__(256) void k_precomp(
    const float* __restrict__ Ain, const float* __restrict__ Bin,
    const float* __restrict__ Cin, const float* __restrict__ Din,
    const float* __restrict__ LS, float* ws)
{
  __shared__ double B0[4096];  // X = h*A ; later: w[0..64) h[64..128) K[128..256)
  __shared__ double B1[4096];  // Z -> N1 -> Ab -> M (in-place squarings)
  const int t = threadIdx.x;
  float*  Wg  = ws + WS_W;
  float*  Gg  = ws + WS_G;
  double* Mgd = (double*)(ws + WS_MD);

  const double step = exp((double)LS[0]);
  const double h = 0.5 * step;

  // X = h*A ; Z = I + X
  for (int idx = t; idx < 4096; idx += 256) {
    double a = h * (double)Ain[idx];
    B0[idx] = a;
    int i = idx >> 6, j = idx & 63;
    B1[idx] = a + ((i == j) ? 1.0 : 0.0);
  }
  __syncthreads();

  const int i_  = t >> 2;         // row 0..63
  const int j0_ = (t & 3) << 4;   // col group of 16

  // Horner: Z <- I + X*Z, 12 times => Z = sum_{k=0}^{13} X^k = N1
  for (int it = 0; it < 12; ++it) {
    double acc[16];
#pragma unroll
    for (int q = 0; q < 16; ++q) acc[q] = 0.0;
    for (int c = 0; c < 64; ++c) {
      double a = B0[(i_ << 6) + c];
#pragma unroll
      for (int q = 0; q < 16; ++q) acc[q] = fma(a, B1[(c << 6) + j0_ + q], acc[q]);
    }
    __syncthreads();
#pragma unroll
    for (int q = 0; q < 16; ++q)
      B1[(i_ << 6) + j0_ + q] = acc[q] + ((i_ == j0_ + q) ? 1.0 : 0.0);
    __syncthreads();
  }

  // Bb = step * N1 @ B (into registers; B0 is dead after Horner)
  double bb = 0.0;
  if (t < 64) {
    for (int c = 0; c < 64; ++c) bb = fma(B1[(t << 6) + c], (double)Bin[c], bb);
    bb *= step;
  }
  __syncthreads();  // all N1 reads done before overwrite

  // Ab = 2*N1 - I, elementwise in place
  for (int idx = t; idx < 4096; idx += 256) {
    int i = idx >> 6, j = idx & 63;
    B1[idx] = 2.0 * B1[idx] - ((i == j) ? 1.0 : 0.0);
  }
  if (t < 64) B0[t] = bb;  // w_0 = Bb
  __syncthreads();

  // h_0 = C @ Ab ; W[0] ; G row r=0 of H-part ; K[0] = C . Bb
  if (t < 64) {
    double hh = 0.0;
    for (int c = 0; c < 64; ++c) hh = fma((double)Cin[c], B1[(c << 6) + t], hh);
    B0[64 + t] = hh;
    Wg[t] = (float)B0[t];
    Gg[(128 + t) * 128 + 0] = (float)hh;
  }
  double kp0 = (t < 64) ? (double)Cin[t] * B0[t] : 0.0;
  if (t < 64) {
#pragma unroll
    for (int s = 32; s; s >>= 1) kp0 += __shfl_xor(kp0, s, 64);
    if (t == 0) B0[128] = kp0;
  }
  __syncthreads();

  // Sequential recurrences, r = 1..127. t<64: w-row-dot; 64<=t<128: h-col-dot.
  const int ii = t & 63;
  for (int r = 1; r < 128; ++r) {
    double nv = 0.0;
    if (t < 64) {
      double s0 = 0, s1 = 0, s2 = 0, s3 = 0;
      for (int c = 0; c < 64; c += 4) {
        s0 = fma(B1[(ii << 6) + c + 0], B0[c + 0], s0);
        s1 = fma(B1[(ii << 6) + c + 1], B0[c + 1], s1);
        s2 = fma(B1[(ii << 6) + c + 2], B0[c + 2], s2);
        s3 = fma(B1[(ii << 6) + c + 3], B0[c + 3], s3);
      }
      nv = (s0 + s1) + (s2 + s3);
    } else if (t < 128) {
      double s0 = 0, s1 = 0, s2 = 0, s3 = 0;
      for (int c = 0; c < 64; c += 4) {
        s0 = fma(B0[64 + c + 0], B1[((c + 0) << 6) + ii], s0);
        s1 = fma(B0[64 + c + 1], B1[((c + 1) << 6) + ii], s1);
        s2 = fma(B0[64 + c + 2], B1[((c + 2) << 6) + ii], s2);
        s3 = fma(B0[64 + c + 3], B1[((c + 3) << 6) + ii], s3);
      }
      nv = (s0 + s1) + (s2 + s3);
    }
    // K[r] = C . w_r  (wave 0 reduce over the fresh nv)
    double kp = (t < 64) ? (double)Cin[ii] * nv : 0.0;
    if (t < 64) {
#pragma unroll
      for (int s = 32; s; s >>= 1) kp += __shfl_xor(kp, s, 64);
    }
    __syncthreads();  // all B0 reads complete
    if (t < 64) {
      B0[ii] = nv;
      Wg[(r << 6) + ii] = (float)nv;
      if (t == 0) B0[128 + r] = kp;
    } else if (t < 128) {
      B0[64 + ii] = nv;
      Gg[(128 + ii) * 128 + r] = (float)nv;
    }
    __syncthreads();
  }

  // M = Ab^128 via 7 in-place squarings (register staging)
  for (int sq = 0; sq < 7; ++sq) {
    double acc[16];
#pragma unroll
    for (int q = 0; q < 16; ++q) acc[q] = 0.0;
    for (int c = 0; c < 64; ++c) {
      double a = B1[(i_ << 6) + c];
#pragma unroll
      for (int q = 0; q < 16; ++q) acc[q] = fma(a, B1[(c << 6) + j0_ + q], acc[q]);
    }
    __syncthreads();
#pragma unroll
    for (int q = 0; q < 16; ++q) B1[(i_ << 6) + j0_ + q] = acc[q];
    __syncthreads();
  }
  for (int idx = t; idx < 4096; idx += 256) Mgd[idx] = B1[idx];

  // G Toeplitz part: G[k][r] = K[r-k] (r>=k) + D*(k==r), K in B0[128..256)
  const float Dval = Din[0];
  for (int idx = t; idx < 16384; idx += 256) {
    int k = idx >> 7, r = idx & 127;
    float v = (r >= k) ? (float)B0[128 + (r - k)] : 0.f;
    if (k == r) v += Dval;
    Gg[idx] = v;
  }
}

// ---------------------------------------------------------------------------
// Kernel B: chunk input vectors  b[rc][i] = sum_k u[rc][k] * W[127-k][i]
// GEMM M=65536, N=64, K=128. Block = 128 rc-rows, 128 threads, 8x8 tiles.
// ---------------------------------------------------------------------------
__global__ __launch_bounds__(128) void k_chunkvec(
    const float* __restrict__ u, const float* __restrict__ Wg,
    float* __restrict__ bout)
{
  __shared__ float As[32 * 132];  // [kk][rcl], transposed u slice
  __shared__ float Bs[32 * 68];   // [kk][i]
  const int t = threadIdx.x;
  const int rc0 = blockIdx.x << 7;
  const int trow = (t >> 3) << 3;
  const int tcol = (t & 7) << 3;
  float acc[8][8];
#pragma unroll
  for (int i = 0; i < 8; ++i)
#pragma unroll
    for (int j = 0; j < 8; ++j) acc[i][j] = 0.f;

  for (int sl = 0; sl < 4; ++sl) {
    for (int it = t; it < 1024; it += 128) {
      int rcl = it >> 3, k4 = (it & 7) << 2;
      float4 v = *(const float4*)&u[((size_t)(rc0 + rcl) << 7) + (sl << 5) + k4];
      As[(k4 + 0) * 132 + rcl] = v.x;
      As[(k4 + 1) * 132 + rcl] = v.y;
      As[(k4 + 2) * 132 + rcl] = v.z;
      As[(k4 + 3) * 132 + rcl] = v.w;
    }
    for (int it = t; it < 512; it += 128) {
      int kk = it >> 4, i4 = (it & 15) << 2;
      *(float4*)&Bs[kk * 68 + i4] =
          *(const float4*)&Wg[((size_t)(127 - ((sl << 5) + kk)) << 6) + i4];
    }
    __syncthreads();
#pragma unroll 4
    for (int kk = 0; kk < 32; ++kk) {
      float av[8], bv[8];
      *(float4*)&av[0] = *(const float4*)&As[kk * 132 + trow];
      *(float4*)&av[4] = *(const float4*)&As[kk * 132 + trow + 4];
      *(float4*)&bv[0] = *(const float4*)&Bs[kk * 68 + tcol];
      *(float4*)&bv[4] = *(const float4*)&Bs[kk * 68 + tcol + 4];
#pragma unroll
      for (int i = 0; i < 8; ++i)
#pragma unroll
        for (int j = 0; j < 8; ++j) acc[i][j] = fmaf(av[i], bv[j], acc[i][j]);
    }
    __syncthreads();
  }
#pragma unroll
  for (int i = 0; i < 8; ++i) {
    size_t base = ((size_t)(rc0 + trow + i) << 6) + tcol;
    *(float4*)&bout[base]     = make_float4(acc[i][0], acc[i][1], acc[i][2], acc[i][3]);
    *(float4*)&bout[base + 4] = make_float4(acc[i][4], acc[i][5], acc[i][6], acc[i][7]);
  }
}

// ---------------------------------------------------------------------------
// Kernel C: per-row chunk-state scan in fp64. X_0 = 0; X_{j+1} = M X_j + b_j.
// One wave per batch row; state one element per lane; matvec via shuffles.
// ---------------------------------------------------------------------------
__global__ __launch_bounds__(64) void k_scan(
    const double* __restrict__ Mg, const float* __restrict__ bv,
    float* __restrict__ Xg)
{
  const int row = blockIdx.x;
  const int lane = threadIdx.x;
  double Mr[64];
#pragma unroll
  for (int c = 0; c < 64; ++c) Mr[c] = Mg[((size_t)lane << 6) + c];
  const float* br = bv + ((size_t)row << 13);
  float* Xr = Xg + ((size_t)row << 13);
  double x = 0.0;
  for (int j = 0; j < 128; ++j) {
    Xr[(j << 6) + lane] = (float)x;
    double bn = (double)br[(j << 6) + lane];
    double a0 = 0, a1 = 0, a2 = 0, a3 = 0;
#pragma unroll
    for (int c = 0; c < 64; c += 4) {
      a0 = fma(Mr[c + 0], __shfl(x, c + 0), a0);
      a1 = fma(Mr[c + 1], __shfl(x, c + 1), a1);
      a2 = fma(Mr[c + 2], __shfl(x, c + 2), a2);
      a3 = fma(Mr[c + 3], __shfl(x, c + 3), a3);
    }
    x = bn + ((a0 + a1) + (a2 + a3));
  }
}

// ---------------------------------------------------------------------------
// Kernel D: main output GEMM. y[rc][r] = sum_{k<128} u[rc][k] G[k][r]
//                                       + sum_i X[rc][i] G[128+i][r]
// M=65536, N=128, K=192. Block = 128 rc-rows, 256 threads, 8x8 tiles.
// ---------------------------------------------------------------------------
__global__ __launch_bounds__(256) void k_main(
    const float* __restrict__ u, const float* __restrict__ Xg,
    const float* __restrict__ Gg, float* __restrict__ out)
{
  __shared__ float As[32 * 132];  // [kk][rcl]
  __shared__ float Bs[32 * 132];  // [kk][r]
  const int t = threadIdx.x;
  const int rc0 = blockIdx.x << 7;
  const int trow = (t >> 4) << 3;
  const int tcol = (t & 15) << 3;
  float acc[8][8];
#pragma unroll
  for (int i = 0; i < 8; ++i)
#pragma unroll
    for (int j = 0; j < 8; ++j) acc[i][j] = 0.f;

  for (int sl = 0; sl < 6; ++sl) {
    const int k0 = sl << 5;
    for (int it = t; it < 1024; it += 256) {
      int rcl = it >> 3, k4 = (it & 7) << 2;
      int kg = k0 + k4;
      float4 v;
      if (kg < 128)
        v = *(const float4*)&u[((size_t)(rc0 + rcl) << 7) + kg];
      else
        v = *(const float4*)&Xg[((size_t)(rc0 + rcl) << 6) + (kg - 128)];
      As[(k4 + 0) * 132 + rcl] = v.x;
      As[(k4 + 1) * 132 + rcl] = v.y;
      As[(k4 + 2) * 132 + rcl] = v.z;
      As[(k4 + 3) * 132 + rcl] = v.w;
    }
    for (int it = t; it < 1024; it += 256) {
      int kk = it >> 5, r4 = (it & 31) << 2;
      *(float4*)&Bs[kk * 132 + r4] = *(const float4*)&Gg[(size_t)(k0 + kk) * 128 + r4];
    }
    __syncthreads();
#pragma unroll 4
    for (int kk = 0; kk < 32; ++kk) {
      float av[8], bv[8];
      *(float4*)&av[0] = *(const float4*)&As[kk * 132 + trow];
      *(float4*)&av[4] = *(const float4*)&As[kk * 132 + trow + 4];
      *(float4*)&bv[0] = *(const float4*)&Bs[kk * 132 + tcol];
      *(float4*)&bv[4] = *(const float4*)&Bs[kk * 132 + tcol + 4];
#pragma unroll
      for (int i = 0; i < 8; ++i)
#pragma unroll
        for (int j = 0; j < 8; ++j) acc[i][j] = fmaf(av[i], bv[j], acc[i][j]);
    }
    __syncthreads();
  }
#pragma unroll
  for (int i = 0; i < 8; ++i) {
    size_t base = ((size_t)(rc0 + trow + i) << 7) + tcol;
    *(float4*)&out[base]     = make_float4(acc[i][0], acc[i][1], acc[i][2], acc[i][3]);
    *(float4*)&out[base + 4] = make_float4(acc[i][4], acc[i][5], acc[i][6], acc[i][7]);
  }
}

// ---------------------------------------------------------------------------
extern "C" void kernel_launch(void* const* d_in, const int* in_sizes, int n_in,
                              void* d_out, int out_size, void* d_ws, size_t ws_size,
                              hipStream_t stream) {
  (void)in_sizes; (void)n_in; (void)out_size; (void)ws_size;
  const float* u  = (const float*)d_in[0];
  const float* A  = (const float*)d_in[1];
  const float* Bv = (const float*)d_in[2];
  const float* Cv = (const float*)d_in[3];
  const float* Dv = (const float*)d_in[4];
  const float* ls = (const float*)d_in[5];
  float* out = (float*)d_out;
  float* ws  = (float*)d_ws;

  k_precomp<<<1, 256, 0, stream>>>(A, Bv, Cv, Dv, ls, ws);
  k_chunkvec<<<512, 128, 0, stream>>>(u, ws + WS_W, ws + WS_BV);
  k_scan<<<512, 64, 0, stream>>>((const double*)(ws + WS_MD), ws + WS_BV, ws + WS_X);
  k_main<<<512, 256, 0, stream>>>(u, ws + WS_X, ws + WS_G, out);
}

// Round 3
// 371.401 us; speedup vs baseline: 2.1631x; 2.1631x over previous
//
#include <hip/hip_runtime.h>
#include <cstddef>

// Problem constants: N=64 state dim, L=16384 seq, BATCH=512, chunk m=128.
static constexpr int RCN = 512 * 128;   // 65536 (row, chunk) pairs

// ws layout (float offsets)
static constexpr size_t WS_W  = 0;       // W[r][i] = (Ab^r Bb)_i, 128x64 fp32
static constexpr size_t WS_G  = 8192;    // fused weights G, 192x128 fp32
static constexpr size_t WS_MD = 32768;   // M = Ab^128, 64x64 DOUBLE (8192 floats)
static constexpr size_t WS_BV = 40960;   // chunk vectors b, RCN x 64 fp32
static constexpr size_t WS_X  = WS_BV + (size_t)RCN * 64;  // chunk states X, RCN x 64 fp32

// ---------------------------------------------------------------------------
// Kernel A: discretize + build all weights. 1 block x 256 threads.
//   Numerics: fp64 for N1 = inv(I-hA) (product-form Neumann, 16 terms),
//   Ab = 2*N1 - I, and the M = Ab^128 squaring chain + its byproducts.
//   W/H built by log-doubling SHARING the squarings (powers <= 128 only, so
//   fp32 storage / fp64 accumulate is safe); K = C.W.
//   LDS: stride-65 rows for doubles -> row AND column access are 2-way (free);
//   B-operand reads are wave-uniform (broadcast). In-place matmuls via
//   register staging + barrier. Total ~13 64x64x64 fp64 matmuls.
// ---------------------------------------------------------------------------
__global__ __launch_bounds__(256) void k_precomp(
    const float* __restrict__ Ain, const float* __restrict__ Bin,
    const float* __restrict__ Cin, const float* __restrict__ Din,
    const float* __restrict__ LS, float* ws)
{
  __shared__ double Xd[64 * 65];   // hA, then hA^(2^k)
  __shared__ double Pd[64 * 65];   // Z -> N1 -> Ab -> P-chain -> M
  __shared__ float  Wf[128 * 65];  // W[r][i], stride 65 (conflict-free col reads)
  __shared__ float  Hf[128 * 65];  // H[r][i] = (C Ab^{r+1})_i
  __shared__ float  Kf[128];

  const int t  = threadIdx.x;
  const int i_ = t & 63;           // output row (per-lane within wave)
  const int j0 = (t >> 6) << 4;    // output col group (wave-uniform)

  float*  Wg  = ws + WS_W;
  float*  Gg  = ws + WS_G;
  double* Mgd = (double*)(ws + WS_MD);

  const double step = exp((double)LS[0]);
  const double h = 0.5 * step;

  // X = h*A ; Z = I + X
  for (int idx = t; idx < 4096; idx += 256) {
    int i = idx >> 6, j = idx & 63;
    double a = h * (double)Ain[idx];
    Xd[i * 65 + j] = a;
    Pd[i * 65 + j] = a + ((i == j) ? 1.0 : 0.0);
  }
  __syncthreads();

  // Product-form Neumann: Z <- Z*(I + X^{2^k}), X <- X^2, k = 1..3
  // => Z = sum_{j=0}^{15} X^j ; truncation ||X||^16 <= 0.1^16 = 1e-16.
  for (int k = 0; k < 3; ++k) {
    // X <- X*X (in place, register-staged)
    {
      double acc[16];
#pragma unroll
      for (int q = 0; q < 16; ++q) acc[q] = 0.0;
      for (int c = 0; c < 64; ++c) {
        double a = Xd[i_ * 65 + c];           // per-lane row read (2-way)
#pragma unroll
        for (int q = 0; q < 16; ++q)
          acc[q] = fma(a, Xd[c * 65 + j0 + q], acc[q]);  // broadcast
      }
      __syncthreads();
#pragma unroll
      for (int q = 0; q < 16; ++q) Xd[i_ * 65 + j0 + q] = acc[q];
      __syncthreads();
    }
    // Z <- Z + Z*X (in place)
    {
      double acc[16], zold[16];
#pragma unroll
      for (int q = 0; q < 16; ++q) acc[q] = 0.0;
      for (int c = 0; c < 64; ++c) {
        double a = Pd[i_ * 65 + c];
#pragma unroll
        for (int q = 0; q < 16; ++q)
          acc[q] = fma(a, Xd[c * 65 + j0 + q], acc[q]);
      }
#pragma unroll
      for (int q = 0; q < 16; ++q) zold[q] = Pd[i_ * 65 + j0 + q];
      __syncthreads();
#pragma unroll
      for (int q = 0; q < 16; ++q) Pd[i_ * 65 + j0 + q] = zold[q] + acc[q];
      __syncthreads();
    }
  }
  // Pd = N1. Bb = step * N1 @ B  -> W[0]
  if (t < 64) {
    double bb = 0.0;
    for (int c = 0; c < 64; ++c) bb = fma(Pd[t * 65 + c], (double)Bin[c], bb);
    Wf[t] = (float)(bb * step);   // W row 0 (stride 65, r=0)
  }
  __syncthreads();  // all N1 reads complete before overwrite

  // Ab = 2*N1 - I (in place)
  for (int idx = t; idx < 4096; idx += 256) {
    int i = idx >> 6, j = idx & 63;
    Pd[i * 65 + j] = 2.0 * Pd[i * 65 + j] - ((i == j) ? 1.0 : 0.0);
  }
  __syncthreads();

  // H[0] = C @ Ab (column reads of Pd: 2-way, free)
  if (t < 64) {
    double hh = 0.0;
    for (int c = 0; c < 64; ++c) hh = fma((double)Cin[c], Pd[c * 65 + t], hh);
    Hf[t] = (float)hh;
  }
  __syncthreads();

  // Log-doubling: entry invariant P = Ab^n (n = 2^k), W[0..n), H[0..n) valid.
  //   W[n+r] = P @ W[r]  (row reads of P + broadcast W)
  //   H[n+r] = H[r] @ P  (broadcast H + column reads of P)
  //   P <- P*P           (shared with the M = Ab^128 chain)
  for (int k = 0; k < 7; ++k) {
    const int n = 1 << k;
    for (int o = t; o < (n << 6); o += 256) {
      int r = o >> 6, ii = o & 63;      // wave-uniform r, per-lane ii
      double aw = 0.0, ah = 0.0;
      for (int c = 0; c < 64; ++c) {
        aw = fma(Pd[ii * 65 + c], (double)Wf[r * 65 + c], aw);
        ah = fma((double)Hf[r * 65 + c], Pd[c * 65 + ii], ah);
      }
      Wf[(n + r) * 65 + ii] = (float)aw;
      Hf[(n + r) * 65 + ii] = (float)ah;
    }
    __syncthreads();
    // P <- P*P (in place, register-staged; barrier also orders W/H writes)
    {
      double acc[16];
#pragma unroll
      for (int q = 0; q < 16; ++q) acc[q] = 0.0;
      for (int c = 0; c < 64; ++c) {
        double a = Pd[i_ * 65 + c];
#pragma unroll
        for (int q = 0; q < 16; ++q)
          acc[q] = fma(a, Pd[c * 65 + j0 + q], acc[q]);
      }
      __syncthreads();
#pragma unroll
      for (int q = 0; q < 16; ++q) Pd[i_ * 65 + j0 + q] = acc[q];
      __syncthreads();
    }
  }
  // Pd = Ab^128 = M (fp64) -> global for k_scan
  for (int idx = t; idx < 4096; idx += 256)
    Mgd[idx] = Pd[(idx >> 6) * 65 + (idx & 63)];

  // K[r] = C . W[r]  (Wf reads: bank (t+i)%32 -> conflict-free via 65 pad)
  if (t < 128) {
    double s = 0.0;
    for (int c = 0; c < 64; ++c) s = fma((double)Cin[c], (double)Wf[t * 65 + c], s);
    Kf[t] = (float)s;
  }
  __syncthreads();

  // W -> global (dense 64-stride for k_chunkvec)
  for (int idx = t; idx < 8192; idx += 256)
    Wg[idx] = Wf[(idx >> 6) * 65 + (idx & 63)];

  // G Toeplitz part: G[k][r] = K[r-k] (r>=k) + D*(k==r)
  const float Dval = Din[0];
  for (int idx = t; idx < 16384; idx += 256) {
    int k = idx >> 7, r = idx & 127;
    float v = (r >= k) ? Kf[r - k] : 0.f;
    if (k == r) v += Dval;
    Gg[idx] = v;
  }
  // G cross-chunk part: G[128+i][r] = H[r][i]
  for (int idx = t; idx < 8192; idx += 256) {
    int i = idx >> 7, r = idx & 127;
    Gg[(128 + i) * 128 + r] = Hf[r * 65 + i];
  }
}

// ---------------------------------------------------------------------------
// Kernel B: chunk input vectors  b[rc][i] = sum_k u[rc][k] * W[127-k][i]
// GEMM M=65536, N=64, K=128. Block = 128 rc-rows, 128 threads, 8x8 tiles.
// ---------------------------------------------------------------------------
__global__ __launch_bounds__(128) void k_chunkvec(
    const float* __restrict__ u, const float* __restrict__ Wg,
    float* __restrict__ bout)
{
  __shared__ float As[32 * 132];  // [kk][rcl], transposed u slice
  __shared__ float Bs[32 * 68];   // [kk][i]
  const int t = threadIdx.x;
  const int rc0 = blockIdx.x << 7;
  const int trow = (t >> 3) << 3;
  const int tcol = (t & 7) << 3;
  float acc[8][8];
#pragma unroll
  for (int i = 0; i < 8; ++i)
#pragma unroll
    for (int j = 0; j < 8; ++j) acc[i][j] = 0.f;

  for (int sl = 0; sl < 4; ++sl) {
    for (int it = t; it < 1024; it += 128) {
      int rcl = it >> 3, k4 = (it & 7) << 2;
      float4 v = *(const float4*)&u[((size_t)(rc0 + rcl) << 7) + (sl << 5) + k4];
      As[(k4 + 0) * 132 + rcl] = v.x;
      As[(k4 + 1) * 132 + rcl] = v.y;
      As[(k4 + 2) * 132 + rcl] = v.z;
      As[(k4 + 3) * 132 + rcl] = v.w;
    }
    for (int it = t; it < 512; it += 128) {
      int kk = it >> 4, i4 = (it & 15) << 2;
      *(float4*)&Bs[kk * 68 + i4] =
          *(const float4*)&Wg[((size_t)(127 - ((sl << 5) + kk)) << 6) + i4];
    }
    __syncthreads();
#pragma unroll 4
    for (int kk = 0; kk < 32; ++kk) {
      float av[8], bv[8];
      *(float4*)&av[0] = *(const float4*)&As[kk * 132 + trow];
      *(float4*)&av[4] = *(const float4*)&As[kk * 132 + trow + 4];
      *(float4*)&bv[0] = *(const float4*)&Bs[kk * 68 + tcol];
      *(float4*)&bv[4] = *(const float4*)&Bs[kk * 68 + tcol + 4];
#pragma unroll
      for (int i = 0; i < 8; ++i)
#pragma unroll
        for (int j = 0; j < 8; ++j) acc[i][j] = fmaf(av[i], bv[j], acc[i][j]);
    }
    __syncthreads();
  }
#pragma unroll
  for (int i = 0; i < 8; ++i) {
    size_t base = ((size_t)(rc0 + trow + i) << 6) + tcol;
    *(float4*)&bout[base]     = make_float4(acc[i][0], acc[i][1], acc[i][2], acc[i][3]);
    *(float4*)&bout[base + 4] = make_float4(acc[i][4], acc[i][5], acc[i][6], acc[i][7]);
  }
}

// ---------------------------------------------------------------------------
// Kernel C: per-row chunk-state scan in fp64. X_0 = 0; X_{j+1} = M X_j + b_j.
// 256 threads/block: thread (i, q) covers M[i][16q..16q+16); partials reduced
// through LDS. 4 waves/block * 2 blocks/CU of latency hiding.
// ---------------------------------------------------------------------------
__global__ __launch_bounds__(256) void k_scan(
    const double* __restrict__ Mg, const float* __restrict__ bv,
    float* __restrict__ Xg)
{
  __shared__ double xs[64];
  __shared__ double part[3 * 64];
  const int t = threadIdx.x;
  const int i = t & 63, q = t >> 6;   // q is wave-uniform
  double Mr[16];
#pragma unroll
  for (int c = 0; c < 16; ++c) Mr[c] = Mg[((size_t)i << 6) + (q << 4) + c];
  const float* br = bv + ((size_t)blockIdx.x << 13);
  float* Xr = Xg + ((size_t)blockIdx.x << 13);
  if (t < 64) xs[t] = 0.0;
  __syncthreads();
  for (int j = 0; j < 128; ++j) {
    double s0 = 0, s1 = 0, s2 = 0, s3 = 0;
#pragma unroll
    for (int c = 0; c < 16; c += 4) {   // xs reads are wave-uniform broadcasts
      s0 = fma(Mr[c + 0], xs[(q << 4) + c + 0], s0);
      s1 = fma(Mr[c + 1], xs[(q << 4) + c + 1], s1);
      s2 = fma(Mr[c + 2], xs[(q << 4) + c + 2], s2);
      s3 = fma(Mr[c + 3], xs[(q << 4) + c + 3], s3);
    }
    double ps = (s0 + s1) + (s2 + s3);
    if (q) part[((q - 1) << 6) + i] = ps;
    __syncthreads();
    if (q == 0) {
      double xold = xs[i];
      Xr[(j << 6) + i] = (float)xold;                 // state at chunk start
      xs[i] = (double)br[(j << 6) + i] + ps + part[i] + part[64 + i] + part[128 + i];
    }
    __syncthreads();
  }
}

// ---------------------------------------------------------------------------
// Kernel D: main output GEMM. y[rc][r] = sum_{k<128} u[rc][k] G[k][r]
//                                       + sum_i X[rc][i] G[128+i][r]
// M=65536, N=128, K=192. Block = 128 rc-rows, 256 threads, 8x8 tiles.
// ---------------------------------------------------------------------------
__global__ __launch_bounds__(256) void k_main(
    const float* __restrict__ u, const float* __restrict__ Xg,
    const float* __restrict__ Gg, float* __restrict__ out)
{
  __shared__ float As[32 * 132];  // [kk][rcl]
  __shared__ float Bs[32 * 132];  // [kk][r]
  const int t = threadIdx.x;
  const int rc0 = blockIdx.x << 7;
  const int trow = (t >> 4) << 3;
  const int tcol = (t & 15) << 3;
  float acc[8][8];
#pragma unroll
  for (int i = 0; i < 8; ++i)
#pragma unroll
    for (int j = 0; j < 8; ++j) acc[i][j] = 0.f;

  for (int sl = 0; sl < 6; ++sl) {
    const int k0 = sl << 5;
    for (int it = t; it < 1024; it += 256) {
      int rcl = it >> 3, k4 = (it & 7) << 2;
      int kg = k0 + k4;
      float4 v;
      if (kg < 128)
        v = *(const float4*)&u[((size_t)(rc0 + rcl) << 7) + kg];
      else
        v = *(const float4*)&Xg[((size_t)(rc0 + rcl) << 6) + (kg - 128)];
      As[(k4 + 0) * 132 + rcl] = v.x;
      As[(k4 + 1) * 132 + rcl] = v.y;
      As[(k4 + 2) * 132 + rcl] = v.z;
      As[(k4 + 3) * 132 + rcl] = v.w;
    }
    for (int it = t; it < 1024; it += 256) {
      int kk = it >> 5, r4 = (it & 31) << 2;
      *(float4*)&Bs[kk * 132 + r4] = *(const float4*)&Gg[(size_t)(k0 + kk) * 128 + r4];
    }
    __syncthreads();
#pragma unroll 4
    for (int kk = 0; kk < 32; ++kk) {
      float av[8], bv[8];
      *(float4*)&av[0] = *(const float4*)&As[kk * 132 + trow];
      *(float4*)&av[4] = *(const float4*)&As[kk * 132 + trow + 4];
      *(float4*)&bv[0] = *(const float4*)&Bs[kk * 132 + tcol];
      *(float4*)&bv[4] = *(const float4*)&Bs[kk * 132 + tcol + 4];
#pragma unroll
      for (int i = 0; i < 8; ++i)
#pragma unroll
        for (int j = 0; j < 8; ++j) acc[i][j] = fmaf(av[i], bv[j], acc[i][j]);
    }
    __syncthreads();
  }
#pragma unroll
  for (int i = 0; i < 8; ++i) {
    size_t base = ((size_t)(rc0 + trow + i) << 7) + tcol;
    *(float4*)&out[base]     = make_float4(acc[i][0], acc[i][1], acc[i][2], acc[i][3]);
    *(float4*)&out[base + 4] = make_float4(acc[i][4], acc[i][5], acc[i][6], acc[i][7]);
  }
}

// ---------------------------------------------------------------------------
extern "C" void kernel_launch(void* const* d_in, const int* in_sizes, int n_in,
                              void* d_out, int out_size, void* d_ws, size_t ws_size,
                              hipStream_t stream) {
  (void)in_sizes; (void)n_in; (void)out_size; (void)ws_size;
  const float* u  = (const float*)d_in[0];
  const float* A  = (const float*)d_in[1];
  const float* Bv = (const float*)d_in[2];
  const float* Cv = (const float*)d_in[3];
  const float* Dv = (const float*)d_in[4];
  const float* ls = (const float*)d_in[5];
  float* out = (float*)d_out;
  float* ws  = (float*)d_ws;

  k_precomp<<<1, 256, 0, stream>>>(A, Bv, Cv, Dv, ls, ws);
  k_chunkvec<<<512, 128, 0, stream>>>(u, ws + WS_W, ws + WS_BV);
  k_scan<<<512, 256, 0, stream>>>((const double*)(ws + WS_MD), ws + WS_BV, ws + WS_X);
  k_main<<<512, 256, 0, stream>>>(u, ws + WS_X, ws + WS_G, out);
}